// Round 1
// baseline (542.641 us; speedup 1.0000x reference)
//
#include <hip/hip_runtime.h>
#include <math.h>

// SSIM loss, fused single pass.
// Input: outputs (16,31,256,256) f32, label same -> 496 images 256x256.
// Separable 11-tap gaussian VALID blur of [x,y,x2,y2,xy] -> SSIM map 246x246,
// global mean, out = 1 - mean.

#define KS    11
#define IMG_H 256
#define IMG_W 256
#define OUTD  246          // 256 - 11 + 1
#define NIMG  496
#define OUT_ROWS 62        // output rows per block (4 chunks: 62,62,62,60)
#define NCHUNKY  4
#define C1F   0.0001f      // (0.01*1)^2
#define C2F   0.0009f      // (0.03*1)^2

struct GaussW { float g[KS]; };

__global__ __launch_bounds__(256)
void ssim_fused_kernel(const float* __restrict__ X, const float* __restrict__ Y,
                       double* __restrict__ accum, GaussW gw) {
    __shared__ float2 rowbuf[KS][IMG_W];   // 11 staged rows, (x,y) interleaved
    __shared__ float  wsum[4];

    const int img    = blockIdx.x;
    const int out_r0 = blockIdx.y * OUT_ROWS;
    const int nout   = min(OUT_ROWS, OUTD - out_r0);   // 62 or 60
    const int nin    = nout + (KS - 1);                // input rows this block
    const int tid    = threadIdx.x;
    const int col    = tid;                            // output column
    const bool active = (col < OUTD);

    const float* Xi = X + (size_t)img * (IMG_H * IMG_W);
    const float* Yi = Y + (size_t)img * (IMG_H * IMG_W);

    float g[KS];
    #pragma unroll
    for (int t = 0; t < KS; ++t) g[t] = gw.g[t];

    // register ring buffers of horizontal-blur values (slot = local_row % 11)
    float rhx[KS], rhy[KS], rhxx[KS], rhyy[KS], rhxy[KS];

    float ssum = 0.0f;

    for (int jj = 0; jj < nin; jj += KS) {
        const int navail = min(KS, nin - jj);
        __syncthreads();
        // stage rows [out_r0+jj, out_r0+jj+navail) of x and y into LDS
        for (int r = 0; r < navail; ++r) {
            const int row = out_r0 + jj + r;
            rowbuf[r][tid] = make_float2(Xi[row * IMG_W + tid],
                                         Yi[row * IMG_W + tid]);
        }
        __syncthreads();

        #pragma unroll
        for (int k = 0; k < KS; ++k) {
            if (k >= navail) break;
            // horizontal blur of 5 maps at (local row jj+k, col)
            float hx = 0.f, hy = 0.f, hxx = 0.f, hyy = 0.f, hxy = 0.f;
            if (active) {
                #pragma unroll
                for (int t = 0; t < KS; ++t) {
                    const float2 v = rowbuf[k][col + t];
                    const float w = g[t];
                    hx  += w * v.x;
                    hy  += w * v.y;
                    hxx += w * v.x * v.x;
                    hyy += w * v.y * v.y;
                    hxy += w * v.x * v.y;
                }
            }
            // ring slot for local row jj+k is k (jj % 11 == 0)
            rhx[k] = hx; rhy[k] = hy; rhxx[k] = hxx; rhyy[k] = hyy; rhxy[k] = hxy;

            const int j = jj + k;          // local input row just completed
            if (j >= KS - 1) {
                const int i = j - (KS - 1);    // local output row
                if (i < nout && active) {
                    // vertical blur: local row i+t lives in slot (k+1+t) % 11
                    float mx = 0.f, my = 0.f, mxx = 0.f, myy = 0.f, mxy = 0.f;
                    #pragma unroll
                    for (int t = 0; t < KS; ++t) {
                        const int s = (k + 1 + t) % KS;   // compile-time
                        const float w = g[t];
                        mx  += w * rhx[s];
                        my  += w * rhy[s];
                        mxx += w * rhxx[s];
                        myy += w * rhyy[s];
                        mxy += w * rhxy[s];
                    }
                    const float vx  = mxx - mx * mx;
                    const float vy  = myy - my * my;
                    const float cov = mxy - mx * my;
                    const float num = (2.f * mx * my + C1F) * (2.f * cov + C2F);
                    const float den = (mx * mx + my * my + C1F) * (vx + vy + C2F);
                    ssum += num / den;
                }
            }
        }
    }

    // block reduction: wave shuffle then cross-wave via LDS
    #pragma unroll
    for (int off = 32; off > 0; off >>= 1)
        ssum += __shfl_down(ssum, off);
    const int lane = tid & 63, wid = tid >> 6;
    if (lane == 0) wsum[wid] = ssum;
    __syncthreads();
    if (tid == 0) {
        const double s = (double)wsum[0] + (double)wsum[1]
                       + (double)wsum[2] + (double)wsum[3];
        atomicAdd(accum, s);
    }
}

__global__ void ssim_finalize_kernel(const double* __restrict__ accum,
                                     float* __restrict__ out) {
    const double cnt = (double)NIMG * OUTD * OUTD;   // 30,015,936
    out[0] = (float)(1.0 - accum[0] / cnt);
}

extern "C" void kernel_launch(void* const* d_in, const int* in_sizes, int n_in,
                              void* d_out, int out_size, void* d_ws, size_t ws_size,
                              hipStream_t stream) {
    (void)in_sizes; (void)n_in; (void)out_size; (void)ws_size;
    const float* X = (const float*)d_in[0];
    const float* Y = (const float*)d_in[1];
    float* out = (float*)d_out;
    double* acc = (double*)d_ws;

    // zero the accumulator (d_ws is re-poisoned before every timed launch)
    hipMemsetAsync(d_ws, 0, sizeof(double), stream);

    // gaussian weights, computed in double on host, normalized
    GaussW gw;
    {
        double gd[KS], s = 0.0;
        for (int i = 0; i < KS; ++i) {
            const double c = (double)i - (KS - 1) / 2.0;
            gd[i] = exp(-(c * c) / (2.0 * 1.5 * 1.5));
            s += gd[i];
        }
        for (int i = 0; i < KS; ++i) gw.g[i] = (float)(gd[i] / s);
    }

    dim3 grid(NIMG, NCHUNKY);
    hipLaunchKernelGGL(ssim_fused_kernel, grid, dim3(256), 0, stream, X, Y, acc, gw);
    hipLaunchKernelGGL(ssim_finalize_kernel, dim3(1), dim3(1), 0, stream, acc, out);
}

// Round 2
// 412.232 us; speedup vs baseline: 1.3163x; 1.3163x over previous
//
#include <hip/hip_runtime.h>
#include <math.h>

// SSIM loss, fused single pass, register ring-buffer version.
// Input: outputs (16,31,256,256) f32 + label -> 496 images 256x256.
// Separable 11-tap gaussian VALID blur of [x,y,x2,y2,xy] -> SSIM 246x246,
// global mean, out = 1 - mean.

#define KS    11
#define IMG_H 256
#define IMG_W 256
#define PADW  268          // IMG_W + 12: tap reads up to col 265, no guard
#define OUTD  246
#define NIMG  496
#define OUT_ROWS 123       // 2 y-chunks x 123 = 246
#define NCHUNKY  2
#define NCHUNKS  13        // ceil((123+10)/11)
#define C1F   0.0001f
#define C2F   0.0009f

struct GaussW { float g[KS]; };

__global__ __launch_bounds__(256)
void ssim_fused_kernel(const float* __restrict__ X, const float* __restrict__ Y,
                       double* __restrict__ accum, GaussW gw) {
    __shared__ float2 rowbuf[KS][PADW];   // 11 staged rows, (x,y) pairs, padded
    __shared__ float  wsum[4];

    const int img    = blockIdx.x;
    const int out_r0 = blockIdx.y * OUT_ROWS;
    const int tid    = threadIdx.x;
    const bool active = (tid < OUTD);

    const float* Xi = X + (size_t)img * (IMG_H * IMG_W);
    const float* Yi = Y + (size_t)img * (IMG_H * IMG_W);

    float g[KS];
    #pragma unroll
    for (int t = 0; t < KS; ++t) g[t] = gw.g[t];

    // register ring buffers of horizontal-blur values; slot = local_row % 11.
    // All indices below are compile-time constants -> stays in VGPRs.
    float rhx[KS], rhy[KS], rhxx[KS], rhyy[KS], rhxy[KS];

    float ssum = 0.0f;

    for (int c = 0; c < NCHUNKS; ++c) {
        const int jj = c * KS;
        __syncthreads();
        // stage 11 rows (row index clamped; clamped rows only feed discarded
        // outputs)
        #pragma unroll
        for (int r = 0; r < KS; ++r) {
            int row = out_r0 + jj + r;
            row = min(row, IMG_H - 1);
            rowbuf[r][tid] = make_float2(Xi[(row << 8) + tid],
                                         Yi[(row << 8) + tid]);
        }
        __syncthreads();

        #pragma unroll
        for (int k = 0; k < KS; ++k) {
            // horizontal blur of 5 maps at (local row jj+k, col tid).
            // cols >= OUTD read pad garbage; their results are never used.
            float hx = 0.f, hy = 0.f, hxx = 0.f, hyy = 0.f, hxy = 0.f;
            #pragma unroll
            for (int t = 0; t < KS; ++t) {
                const float2 v = rowbuf[k][tid + t];
                const float w  = g[t];
                const float wx = w * v.x;
                const float wy = w * v.y;
                hx  += wx;
                hy  += wy;
                hxx += wx * v.x;
                hyy += wy * v.y;
                hxy += wx * v.y;
            }
            rhx[k] = hx; rhy[k] = hy; rhxx[k] = hxx; rhyy[k] = hyy; rhxy[k] = hxy;

            const int j = jj + k;              // local input row just completed
            const int i = j - (KS - 1);        // local output row
            if (j >= KS - 1 && i < OUT_ROWS) { // wave-uniform branch
                // vertical blur: local row i+t lives in slot (k+1+t) % 11
                float mx = 0.f, my = 0.f, mxx = 0.f, myy = 0.f, mxy = 0.f;
                #pragma unroll
                for (int t = 0; t < KS; ++t) {
                    const int s = (k + 1 + t) % KS;   // compile-time
                    const float w = g[t];
                    mx  += w * rhx[s];
                    my  += w * rhy[s];
                    mxx += w * rhxx[s];
                    myy += w * rhyy[s];
                    mxy += w * rhxy[s];
                }
                const float vx  = mxx - mx * mx;
                const float vy  = myy - my * my;
                const float cov = mxy - mx * my;
                const float num = (2.f * mx * my + C1F) * (2.f * cov + C2F);
                const float den = (mx * mx + my * my + C1F) * (vx + vy + C2F);
                const float val = num * __builtin_amdgcn_rcpf(den);
                ssum += active ? val : 0.f;
            }
        }
    }

    // block reduction: wave shuffle then cross-wave via LDS
    #pragma unroll
    for (int off = 32; off > 0; off >>= 1)
        ssum += __shfl_down(ssum, off);
    const int lane = tid & 63, wid = tid >> 6;
    if (lane == 0) wsum[wid] = ssum;
    __syncthreads();
    if (tid == 0) {
        const double s = (double)wsum[0] + (double)wsum[1]
                       + (double)wsum[2] + (double)wsum[3];
        atomicAdd(accum, s);
    }
}

__global__ void ssim_finalize_kernel(const double* __restrict__ accum,
                                     float* __restrict__ out) {
    const double cnt = (double)NIMG * OUTD * OUTD;   // 30,015,936
    out[0] = (float)(1.0 - accum[0] / cnt);
}

extern "C" void kernel_launch(void* const* d_in, const int* in_sizes, int n_in,
                              void* d_out, int out_size, void* d_ws, size_t ws_size,
                              hipStream_t stream) {
    (void)in_sizes; (void)n_in; (void)out_size; (void)ws_size;
    const float* X = (const float*)d_in[0];
    const float* Y = (const float*)d_in[1];
    float* out = (float*)d_out;
    double* acc = (double*)d_ws;

    hipMemsetAsync(d_ws, 0, sizeof(double), stream);

    GaussW gw;
    {
        double gd[KS], s = 0.0;
        for (int i = 0; i < KS; ++i) {
            const double c = (double)i - (KS - 1) / 2.0;
            gd[i] = exp(-(c * c) / (2.0 * 1.5 * 1.5));
            s += gd[i];
        }
        for (int i = 0; i < KS; ++i) gw.g[i] = (float)(gd[i] / s);
    }

    dim3 grid(NIMG, NCHUNKY);
    hipLaunchKernelGGL(ssim_fused_kernel, grid, dim3(256), 0, stream, X, Y, acc, gw);
    hipLaunchKernelGGL(ssim_finalize_kernel, dim3(1), dim3(1), 0, stream, acc, out);
}

// Round 3
// 345.705 us; speedup vs baseline: 1.5697x; 1.1924x over previous
//
#include <hip/hip_runtime.h>
#include <math.h>

// SSIM loss, fused single pass, register ring-buffer version.
// R3 change: __launch_bounds__(256, 4) -> VGPR cap 128 (was implicit 64),
// letting the 5x11 ring buffers live in registers instead of scratch.

#define KS    11
#define IMG_H 256
#define IMG_W 256
#define PADW  268          // IMG_W + 12: tap reads up to col 265, no guard
#define OUTD  246
#define NIMG  496
#define OUT_ROWS 123       // 2 y-chunks x 123 = 246
#define NCHUNKY  2
#define NCHUNKS  13        // ceil((123+10)/11)
#define C1F   0.0001f
#define C2F   0.0009f

struct GaussW { float g[KS]; };

__global__ __launch_bounds__(256, 4)
void ssim_fused_kernel(const float* __restrict__ X, const float* __restrict__ Y,
                       double* __restrict__ accum, GaussW gw) {
    __shared__ float2 rowbuf[KS][PADW];   // 11 staged rows, (x,y) pairs, padded
    __shared__ float  wsum[4];

    const int img    = blockIdx.x;
    const int out_r0 = blockIdx.y * OUT_ROWS;
    const int tid    = threadIdx.x;
    const bool active = (tid < OUTD);

    const float* Xi = X + (size_t)img * (IMG_H * IMG_W);
    const float* Yi = Y + (size_t)img * (IMG_H * IMG_W);

    float g[KS];
    #pragma unroll
    for (int t = 0; t < KS; ++t) g[t] = gw.g[t];

    // register ring buffers of horizontal-blur values; slot = local_row % 11.
    // All indices below are compile-time constants -> stays in VGPRs.
    float rhx[KS], rhy[KS], rhxx[KS], rhyy[KS], rhxy[KS];

    float ssum = 0.0f;

    for (int c = 0; c < NCHUNKS; ++c) {
        const int jj = c * KS;
        __syncthreads();
        // stage 11 rows (row index clamped; clamped rows only feed discarded
        // outputs)
        #pragma unroll
        for (int r = 0; r < KS; ++r) {
            int row = out_r0 + jj + r;
            row = min(row, IMG_H - 1);
            rowbuf[r][tid] = make_float2(Xi[(row << 8) + tid],
                                         Yi[(row << 8) + tid]);
        }
        __syncthreads();

        #pragma unroll
        for (int k = 0; k < KS; ++k) {
            // horizontal blur of 5 maps at (local row jj+k, col tid).
            // cols >= OUTD read pad garbage; their results are never used.
            float hx = 0.f, hy = 0.f, hxx = 0.f, hyy = 0.f, hxy = 0.f;
            #pragma unroll
            for (int t = 0; t < KS; ++t) {
                const float2 v = rowbuf[k][tid + t];
                const float w  = g[t];
                const float wx = w * v.x;
                const float wy = w * v.y;
                hx  += wx;
                hy  += wy;
                hxx += wx * v.x;
                hyy += wy * v.y;
                hxy += wx * v.y;
            }
            rhx[k] = hx; rhy[k] = hy; rhxx[k] = hxx; rhyy[k] = hyy; rhxy[k] = hxy;

            const int j = jj + k;              // local input row just completed
            const int i = j - (KS - 1);        // local output row
            if (j >= KS - 1 && i < OUT_ROWS) { // wave-uniform branch
                // vertical blur: local row i+t lives in slot (k+1+t) % 11
                float mx = 0.f, my = 0.f, mxx = 0.f, myy = 0.f, mxy = 0.f;
                #pragma unroll
                for (int t = 0; t < KS; ++t) {
                    const int s = (k + 1 + t) % KS;   // compile-time
                    const float w = g[t];
                    mx  += w * rhx[s];
                    my  += w * rhy[s];
                    mxx += w * rhxx[s];
                    myy += w * rhyy[s];
                    mxy += w * rhxy[s];
                }
                const float vx  = mxx - mx * mx;
                const float vy  = myy - my * my;
                const float cov = mxy - mx * my;
                const float num = (2.f * mx * my + C1F) * (2.f * cov + C2F);
                const float den = (mx * mx + my * my + C1F) * (vx + vy + C2F);
                const float val = num * __builtin_amdgcn_rcpf(den);
                ssum += active ? val : 0.f;
            }
        }
    }

    // block reduction: wave shuffle then cross-wave via LDS
    #pragma unroll
    for (int off = 32; off > 0; off >>= 1)
        ssum += __shfl_down(ssum, off);
    const int lane = tid & 63, wid = tid >> 6;
    if (lane == 0) wsum[wid] = ssum;
    __syncthreads();
    if (tid == 0) {
        const double s = (double)wsum[0] + (double)wsum[1]
                       + (double)wsum[2] + (double)wsum[3];
        atomicAdd(accum, s);
    }
}

__global__ void ssim_finalize_kernel(const double* __restrict__ accum,
                                     float* __restrict__ out) {
    const double cnt = (double)NIMG * OUTD * OUTD;   // 30,015,936
    out[0] = (float)(1.0 - accum[0] / cnt);
}

extern "C" void kernel_launch(void* const* d_in, const int* in_sizes, int n_in,
                              void* d_out, int out_size, void* d_ws, size_t ws_size,
                              hipStream_t stream) {
    (void)in_sizes; (void)n_in; (void)out_size; (void)ws_size;
    const float* X = (const float*)d_in[0];
    const float* Y = (const float*)d_in[1];
    float* out = (float*)d_out;
    double* acc = (double*)d_ws;

    hipMemsetAsync(d_ws, 0, sizeof(double), stream);

    GaussW gw;
    {
        double gd[KS], s = 0.0;
        for (int i = 0; i < KS; ++i) {
            const double c = (double)i - (KS - 1) / 2.0;
            gd[i] = exp(-(c * c) / (2.0 * 1.5 * 1.5));
            s += gd[i];
        }
        for (int i = 0; i < KS; ++i) gw.g[i] = (float)(gd[i] / s);
    }

    dim3 grid(NIMG, NCHUNKY);
    hipLaunchKernelGGL(ssim_fused_kernel, grid, dim3(256), 0, stream, X, Y, acc, gw);
    hipLaunchKernelGGL(ssim_finalize_kernel, dim3(1), dim3(1), 0, stream, acc, out);
}

// Round 4
// 343.633 us; speedup vs baseline: 1.5791x; 1.0060x over previous
//
#include <hip/hip_runtime.h>
#include <math.h>

// SSIM loss, fused single pass.
// R4: ring buffers as 55 NAMED scalars (macro-unrolled ring phases) so they
// are SSA by construction -> guaranteed VGPRs. R2/R3 showed float[11] rings
// indexed by unrolled loop vars fail SROA (VGPR_Count 52/56 => scratch).

#define KS    11
#define IMG_H 256
#define IMG_W 256
#define PADW  268          // tap reads up to col 265, no guard needed
#define OUTD  246
#define NIMG  496
#define OUT_ROWS 123       // 2 y-chunks x 123 = 246
#define NCHUNKY  2
#define NCHUNKS  13        // ceil((123+10)/11)
#define C1F   0.0001f
#define C2F   0.0009f

// 11-tap gaussian (sigma=1.5), normalized; computed in double offline.
__device__ constexpr float GW[KS] = {
    0.00102838f, 0.00759876f, 0.03600077f, 0.10936068f, 0.21300554f,
    0.26601173f,
    0.21300554f, 0.10936068f, 0.03600077f, 0.00759876f, 0.00102838f
};

// horizontal blur of row K of the staged tile, result -> ring slot C
#define HBLUR_STORE(K, C)                                                  \
  do {                                                                     \
    float hx = 0.f, hy = 0.f, hxx = 0.f, hyy = 0.f, hxy = 0.f;             \
    _Pragma("unroll")                                                      \
    for (int t = 0; t < KS; ++t) {                                         \
      const float2 v = rowbuf[K][tid + t];                                 \
      const float w  = GW[t];                                              \
      const float wx = w * v.x, wy = w * v.y;                              \
      hx  += wx;  hy  += wy;                                               \
      hxx += wx * v.x;  hyy += wy * v.y;  hxy += wx * v.y;                 \
    }                                                                      \
    sx##C = hx; sy##C = hy; sxx##C = hxx; syy##C = hyy; sxy##C = hxy;      \
  } while (0)

#define VDOT(M, t0,t1,t2,t3,t4,t5,t6,t7,t8,t9,t10)                         \
  (GW[0]*M##t0 + GW[1]*M##t1 + GW[2]*M##t2 + GW[3]*M##t3 + GW[4]*M##t4     \
 + GW[5]*M##t5 + GW[6]*M##t6 + GW[7]*M##t7 + GW[8]*M##t8 + GW[9]*M##t9     \
 + GW[10]*M##t10)

// one ring phase: h-blur row jj+K into slot K (== t10), then if a full 11-row
// window is resident, v-blur (taps read slots (K+1+t)%11 = t0..t10) + SSIM.
#define STEP(K, t0,t1,t2,t3,t4,t5,t6,t7,t8,t9,t10)                         \
  HBLUR_STORE(K, t10);                                                     \
  {                                                                        \
    const int jrow = jj + K;                                               \
    const int irow = jrow - (KS - 1);                                      \
    if (jrow >= KS - 1 && irow < OUT_ROWS) {   /* wave-uniform */          \
      const float mx  = VDOT(sx,  t0,t1,t2,t3,t4,t5,t6,t7,t8,t9,t10);     \
      const float my  = VDOT(sy,  t0,t1,t2,t3,t4,t5,t6,t7,t8,t9,t10);     \
      const float mxx = VDOT(sxx, t0,t1,t2,t3,t4,t5,t6,t7,t8,t9,t10);     \
      const float myy = VDOT(syy, t0,t1,t2,t3,t4,t5,t6,t7,t8,t9,t10);     \
      const float mxy = VDOT(sxy, t0,t1,t2,t3,t4,t5,t6,t7,t8,t9,t10);     \
      const float vx  = mxx - mx * mx;                                     \
      const float vy  = myy - my * my;                                     \
      const float cov = mxy - mx * my;                                     \
      const float num = (2.f * mx * my + C1F) * (2.f * cov + C2F);         \
      const float den = (mx * mx + my * my + C1F) * (vx + vy + C2F);       \
      ssum += active ? num * __builtin_amdgcn_rcpf(den) : 0.f;             \
    }                                                                      \
  }

__global__ __launch_bounds__(256, 4)
void ssim_fused_kernel(const float* __restrict__ X, const float* __restrict__ Y,
                       double* __restrict__ accum) {
    __shared__ float2 rowbuf[KS][PADW];
    __shared__ float  wsum[4];

    const int img    = blockIdx.x;
    const int out_r0 = blockIdx.y * OUT_ROWS;
    const int tid    = threadIdx.x;
    const bool active = (tid < OUTD);

    const float* Xi = X + (size_t)img * (IMG_H * IMG_W);
    const float* Yi = Y + (size_t)img * (IMG_H * IMG_W);

    // 55 named ring registers (slot = local_row % 11)
    float sx0=0,sx1=0,sx2=0,sx3=0,sx4=0,sx5=0,sx6=0,sx7=0,sx8=0,sx9=0,sx10=0;
    float sy0=0,sy1=0,sy2=0,sy3=0,sy4=0,sy5=0,sy6=0,sy7=0,sy8=0,sy9=0,sy10=0;
    float sxx0=0,sxx1=0,sxx2=0,sxx3=0,sxx4=0,sxx5=0,sxx6=0,sxx7=0,sxx8=0,sxx9=0,sxx10=0;
    float syy0=0,syy1=0,syy2=0,syy3=0,syy4=0,syy5=0,syy6=0,syy7=0,syy8=0,syy9=0,syy10=0;
    float sxy0=0,sxy1=0,sxy2=0,sxy3=0,sxy4=0,sxy5=0,sxy6=0,sxy7=0,sxy8=0,sxy9=0,sxy10=0;

    float ssum = 0.0f;

    for (int c = 0; c < NCHUNKS; ++c) {
        const int jj = c * KS;
        __syncthreads();
        #pragma unroll
        for (int r = 0; r < KS; ++r) {
            int row = out_r0 + jj + r;
            row = min(row, IMG_H - 1);   // clamped rows feed discarded outputs
            rowbuf[r][tid] = make_float2(Xi[(row << 8) + tid],
                                         Yi[(row << 8) + tid]);
        }
        __syncthreads();

        STEP(0,  1,2,3,4,5,6,7,8,9,10,0)
        STEP(1,  2,3,4,5,6,7,8,9,10,0,1)
        STEP(2,  3,4,5,6,7,8,9,10,0,1,2)
        STEP(3,  4,5,6,7,8,9,10,0,1,2,3)
        STEP(4,  5,6,7,8,9,10,0,1,2,3,4)
        STEP(5,  6,7,8,9,10,0,1,2,3,4,5)
        STEP(6,  7,8,9,10,0,1,2,3,4,5,6)
        STEP(7,  8,9,10,0,1,2,3,4,5,6,7)
        STEP(8,  9,10,0,1,2,3,4,5,6,7,8)
        STEP(9,  10,0,1,2,3,4,5,6,7,8,9)
        STEP(10, 0,1,2,3,4,5,6,7,8,9,10)
    }

    // block reduction
    #pragma unroll
    for (int off = 32; off > 0; off >>= 1)
        ssum += __shfl_down(ssum, off);
    const int lane = tid & 63, wid = tid >> 6;
    if (lane == 0) wsum[wid] = ssum;
    __syncthreads();
    if (tid == 0) {
        const double s = (double)wsum[0] + (double)wsum[1]
                       + (double)wsum[2] + (double)wsum[3];
        atomicAdd(accum, s);
    }
}

__global__ void ssim_finalize_kernel(const double* __restrict__ accum,
                                     float* __restrict__ out) {
    const double cnt = (double)NIMG * OUTD * OUTD;   // 30,015,936
    out[0] = (float)(1.0 - accum[0] / cnt);
}

extern "C" void kernel_launch(void* const* d_in, const int* in_sizes, int n_in,
                              void* d_out, int out_size, void* d_ws, size_t ws_size,
                              hipStream_t stream) {
    (void)in_sizes; (void)n_in; (void)out_size; (void)ws_size;
    const float* X = (const float*)d_in[0];
    const float* Y = (const float*)d_in[1];
    float* out = (float*)d_out;
    double* acc = (double*)d_ws;

    hipMemsetAsync(d_ws, 0, sizeof(double), stream);

    dim3 grid(NIMG, NCHUNKY);
    hipLaunchKernelGGL(ssim_fused_kernel, grid, dim3(256), 0, stream, X, Y, acc);
    hipLaunchKernelGGL(ssim_finalize_kernel, dim3(1), dim3(1), 0, stream, acc, out);
}